// Round 9
// baseline (789.969 us; speedup 1.0000x reference)
//
#include <hip/hip_runtime.h>
#include <hip/hip_fp16.h>

#define FEATS 512
#define HIDDEN 64
#define CLASSES 64
#define DEPTH 10
#define ALPHA 0.1f

#define BUCKET_BITS 8
#define BUCKET 256
#define NB_C 391          // ceil(100000 / 256) dst buckets
#define NQT 4             // src quartiles (src >> 15)
#define QT_SHIFT 15
#define NK_C (NQT * NB_C) // 1564 combined (qt, bucket) keys
#define K3_CHUNK 8192
#define K3_THREADS 512

typedef __attribute__((ext_vector_type(8))) short short8;
typedef __attribute__((ext_vector_type(4))) float f32x4;

__device__ __forceinline__ unsigned short bf16_hi(float f) {
    unsigned u = __float_as_uint(f);
    unsigned r = u + 0x7FFF + ((u >> 16) & 1);   // RNE
    return (unsigned short)(r >> 16);
}
__device__ __forceinline__ float bf16_tof(unsigned short h) {
    return __uint_as_float(((unsigned)h) << 16);
}

// ---------------- K1: (qt,bucket) histogram (LDS-aggregated) ----------------
__global__ __launch_bounds__(256) void bucket_hist_kernel(const int* __restrict__ src,
                                                          const int* __restrict__ dst,
                                                          int* __restrict__ bcnt,
                                                          int NB, int NK, int E) {
    __shared__ int h[NK_C];
    for (int j = threadIdx.x; j < NK; j += 256) h[j] = 0;
    __syncthreads();
    int i = blockIdx.x * 256 + threadIdx.x;
    int stride = gridDim.x * 256;
    for (; i < E; i += stride) {
        int kq = (src[i] >> QT_SHIFT) * NB + (dst[i] >> BUCKET_BITS);
        atomicAdd(&h[kq], 1);
    }
    __syncthreads();
    for (int j = threadIdx.x; j < NK; j += 256) {
        int v = h[j];
        if (v) atomicAdd(&bcnt[j], v);
    }
}

// ---------------- K2: scan bucket counts -> bptr, gcur, rowq sentinels -------
__global__ __launch_bounds__(1024) void bucket_scan_kernel(const int* __restrict__ bcnt,
                                                           int* __restrict__ bptr,
                                                           int* __restrict__ gcur,
                                                           int* __restrict__ rowq,
                                                           int NB, int NK, int N, int E) {
    __shared__ int sd[1024];
    int t = threadIdx.x;
    int i0 = 2 * t, i1 = 2 * t + 1;
    int a = (i0 < NK) ? bcnt[i0] : 0;
    int b = (i1 < NK) ? bcnt[i1] : 0;
    int s = a + b;
    sd[t] = s;
    __syncthreads();
    for (int off = 1; off < 1024; off <<= 1) {
        int v = (t >= off) ? sd[t - off] : 0;
        __syncthreads();
        sd[t] += v;
        __syncthreads();
    }
    int excl = sd[t] - s;
    if (i0 < NK) { bptr[i0] = excl;     gcur[i0] = excl; }
    if (i1 < NK) { bptr[i1] = excl + a; gcur[i1] = excl + a; }
    if (t == 0) bptr[NK] = E;
    __syncthreads();   // orders the global bptr writes within this block
    if (t < NQT) rowq[t * (N + 1) + N] = bptr[(t + 1) * NB];
}

// ---------------- K3: partition edges by (qt,bucket), packed src|ldst --------
__global__ __launch_bounds__(K3_THREADS) void bucket_scatter_kernel(const int* __restrict__ src,
                                                                    const int* __restrict__ dst,
                                                                    int* __restrict__ gcur,
                                                                    int* __restrict__ part,
                                                                    int NB, int NK, int E) {
    __shared__ int hist[NK_C];
    __shared__ int base[NK_C];
    int cbase = blockIdx.x * K3_CHUNK;
    for (int j = threadIdx.x; j < NK; j += K3_THREADS) hist[j] = 0;
    __syncthreads();
    for (int k = 0; k < K3_CHUNK; k += K3_THREADS) {
        int i = cbase + k + threadIdx.x;
        if (i < E) {
            int kq = (src[i] >> QT_SHIFT) * NB + (dst[i] >> BUCKET_BITS);
            atomicAdd(&hist[kq], 1);
        }
    }
    __syncthreads();
    for (int j = threadIdx.x; j < NK; j += K3_THREADS) {
        int h = hist[j];
        base[j] = (h > 0) ? atomicAdd(&gcur[j], h) : 0;
        hist[j] = 0;   // reuse as local cursor
    }
    __syncthreads();
    for (int k = 0; k < K3_CHUNK; k += K3_THREADS) {
        int i = cbase + k + threadIdx.x;
        if (i < E) {
            int sv = src[i], d = dst[i];
            int kq = (sv >> QT_SHIFT) * NB + (d >> BUCKET_BITS);
            int off = atomicAdd(&hist[kq], 1);
            part[(size_t)(base[kq] + off)] = (sv << BUCKET_BITS) | (d & (BUCKET - 1));
        }
    }
}

// ---------------- K4: per-(qt,bucket) exact CSR ----------------
__global__ __launch_bounds__(256) void part_to_csr_kernel(const int* __restrict__ bptr,
                                                          const int* __restrict__ part,
                                                          int* __restrict__ rowq,
                                                          int* __restrict__ csr_src,
                                                          int NB, int N) {
    __shared__ int cnt[BUCKET];
    __shared__ int cur[BUCKET];
    __shared__ int wsum[4];
    int kb = blockIdx.x;
    int qt = kb / NB;
    int bb = kb - qt * NB;
    int lo = bb << BUCKET_BITS;
    int tid = threadIdx.x;
    int p0 = bptr[kb], p1 = bptr[kb + 1];
    cnt[tid] = 0;
    __syncthreads();
    for (int i = p0 + tid; i < p1; i += 256) {
        atomicAdd(&cnt[part[i] & (BUCKET - 1)], 1);
    }
    __syncthreads();
    {
        int wv = tid >> 6, ln = tid & 63;
        int v = cnt[tid];
        int incl = v;
#pragma unroll
        for (int off = 1; off < 64; off <<= 1) {
            int t = __shfl_up(incl, off);
            if (ln >= off) incl += t;
        }
        if (ln == 63) wsum[wv] = incl;
        __syncthreads();
        int woff = 0;
#pragma unroll
        for (int w = 0; w < 4; ++w)
            if (w < wv) woff += wsum[w];
        int excl = woff + incl - v;
        if (lo + tid < N) rowq[qt * (N + 1) + lo + tid] = p0 + excl;
        cur[tid] = excl;
    }
    __syncthreads();
    for (int i = p0 + tid; i < p1; i += 256) {
        int pe = part[i];
        int off = atomicAdd(&cur[pe & (BUCKET - 1)], 1);
        csr_src[p0 + off] = ((unsigned)pe) >> BUCKET_BITS;
    }
}

// ---------------- norm: degree from the 4 rowq slices -> inv_sqrt ------------
__global__ __launch_bounds__(256) void norm_kernel(const int* __restrict__ rowq,
                                                   float* __restrict__ inv_sqrt, int N) {
    int i = blockIdx.x * 256 + threadIdx.x;
    if (i >= N) return;
    int deg = 0;
#pragma unroll
    for (int q = 0; q < NQT; ++q) {
        deg += rowq[q * (N + 1) + i + 1] - rowq[q * (N + 1) + i];
    }
    inv_sqrt[i] = rsqrtf((float)(deg < 1 ? 1 : deg));
}

// ---------------- pack W1/W2 into MFMA B-fragment order, split bf16 hi/lo ----
__global__ __launch_bounds__(256) void pack_w_kernel(const float* __restrict__ W1,
                                                     const float* __restrict__ W2,
                                                     unsigned short* __restrict__ w1h,
                                                     unsigned short* __restrict__ w1l,
                                                     unsigned short* __restrict__ w2h,
                                                     unsigned short* __restrict__ w2l) {
    int id = blockIdx.x * blockDim.x + threadIdx.x;
    if (id < 4096) {
        int lane = id & 63, f = (id >> 6) & 3, ks = id >> 8;
        int col = f * 16 + (lane & 15);
        int k0 = ks * 32 + (lane >> 4) * 8;
#pragma unroll
        for (int i = 0; i < 8; ++i) {
            float v = W1[(k0 + i) * HIDDEN + col];
            unsigned short h = bf16_hi(v);
            w1h[id * 8 + i] = h;
            w1l[id * 8 + i] = bf16_hi(v - bf16_tof(h));
        }
    } else if (id < 4096 + 512) {
        int p = id - 4096;
        int lane = p & 63, f = (p >> 6) & 3, ks = p >> 8;
        int col = f * 16 + (lane & 15);
        int k0 = ks * 32 + (lane >> 4) * 8;
#pragma unroll
        for (int i = 0; i < 8; ++i) {
            float v = W2[(k0 + i) * CLASSES + col];
            unsigned short h = bf16_hi(v);
            w2h[p * 8 + i] = h;
            w2l[p * 8 + i] = bf16_hi(v - bf16_tof(h));
        }
    }
}

// ------- MLP via split-bf16 MFMA: h0 = relu(x@W1+b1)@W2+b2; also u0 = h0*is --
__global__ __launch_bounds__(256) void mlp_mfma_kernel(const float* __restrict__ x,
                                                       const unsigned short* __restrict__ w1h,
                                                       const unsigned short* __restrict__ w1l,
                                                       const float* __restrict__ b1,
                                                       const unsigned short* __restrict__ w2h,
                                                       const unsigned short* __restrict__ w2l,
                                                       const float* __restrict__ b2,
                                                       const float* __restrict__ is,
                                                       __half* __restrict__ h0h,
                                                       __half* __restrict__ u0,
                                                       int N) {
    __shared__ float hs[4][16][68];
    int wave = threadIdx.x >> 6;
    int lane = threadIdx.x & 63;
    int tile = blockIdx.x * 4 + wave;
    if (tile * 16 >= N) return;

    int row = lane & 15;
    int koff = (lane >> 4) * 8;
    const short8* w1hv = (const short8*)w1h;
    const short8* w1lv = (const short8*)w1l;
    const short8* w2hv = (const short8*)w2h;
    const short8* w2lv = (const short8*)w2l;

    f32x4 c[4] = {};
    const float* xrow = x + (size_t)(tile * 16 + row) * FEATS + koff;
#pragma unroll 4
    for (int ks = 0; ks < 16; ++ks) {
        float4 a0 = *(const float4*)(xrow + ks * 32);
        float4 a1 = *(const float4*)(xrow + ks * 32 + 4);
        float av[8] = {a0.x, a0.y, a0.z, a0.w, a1.x, a1.y, a1.z, a1.w};
        short8 ah, al;
#pragma unroll
        for (int j = 0; j < 8; ++j) {
            unsigned short h = bf16_hi(av[j]);
            ah[j] = (short)h;
            al[j] = (short)bf16_hi(av[j] - bf16_tof(h));
        }
#pragma unroll
        for (int f = 0; f < 4; ++f) {
            short8 bh = w1hv[(ks * 4 + f) * 64 + lane];
            short8 bl = w1lv[(ks * 4 + f) * 64 + lane];
            c[f] = __builtin_amdgcn_mfma_f32_16x16x32_bf16(ah, bh, c[f], 0, 0, 0);
            c[f] = __builtin_amdgcn_mfma_f32_16x16x32_bf16(ah, bl, c[f], 0, 0, 0);
            c[f] = __builtin_amdgcn_mfma_f32_16x16x32_bf16(al, bh, c[f], 0, 0, 0);
        }
    }
#pragma unroll
    for (int f = 0; f < 4; ++f) {
        float bias = b1[f * 16 + (lane & 15)];
#pragma unroll
        for (int r = 0; r < 4; ++r) {
            hs[wave][(lane >> 4) * 4 + r][f * 16 + (lane & 15)] = fmaxf(c[f][r] + bias, 0.0f);
        }
    }

    f32x4 c2[4] = {};
#pragma unroll
    for (int ks = 0; ks < 2; ++ks) {
        float4 a0 = *(const float4*)&hs[wave][row][ks * 32 + koff];
        float4 a1 = *(const float4*)&hs[wave][row][ks * 32 + koff + 4];
        float av[8] = {a0.x, a0.y, a0.z, a0.w, a1.x, a1.y, a1.z, a1.w};
        short8 ah, al;
#pragma unroll
        for (int j = 0; j < 8; ++j) {
            unsigned short h = bf16_hi(av[j]);
            ah[j] = (short)h;
            al[j] = (short)bf16_hi(av[j] - bf16_tof(h));
        }
#pragma unroll
        for (int f = 0; f < 4; ++f) {
            short8 bh = w2hv[(ks * 4 + f) * 64 + lane];
            short8 bl = w2lv[(ks * 4 + f) * 64 + lane];
            c2[f] = __builtin_amdgcn_mfma_f32_16x16x32_bf16(ah, bh, c2[f], 0, 0, 0);
            c2[f] = __builtin_amdgcn_mfma_f32_16x16x32_bf16(ah, bl, c2[f], 0, 0, 0);
            c2[f] = __builtin_amdgcn_mfma_f32_16x16x32_bf16(al, bh, c2[f], 0, 0, 0);
        }
    }
    float isv[4];
#pragma unroll
    for (int r = 0; r < 4; ++r) {
        int n = tile * 16 + (lane >> 4) * 4 + r;
        isv[r] = is[n];
    }
#pragma unroll
    for (int f = 0; f < 4; ++f) {
        float bias = b2[f * 16 + (lane & 15)];
#pragma unroll
        for (int r = 0; r < 4; ++r) {
            int n = tile * 16 + (lane >> 4) * 4 + r;
            float v = c2[f][r] + bias;
            h0h[(size_t)n * CLASSES + f * 16 + (lane & 15)] = __float2half(v);
            u0[(size_t)n * CLASSES + f * 16 + (lane & 15)] = __float2half(v * isv[r]);
        }
    }
}

// -------- propagation, src-quartile-phased for L2 residency -------------------
// wave per node; grp=lane>>3 selects edge, sub=lane&7 selects 8-feature slice.
// qt phases iterate 4MB slices of u so concurrent waves share an L2-resident set.
__global__ __launch_bounds__(256) void prop_kernel(const int* __restrict__ rowq,
                                                   const int* __restrict__ csr_src,
                                                   const float* __restrict__ is,
                                                   const __half* __restrict__ u_in,
                                                   const __half* __restrict__ h0h,
                                                   __half* __restrict__ u_out,
                                                   float* __restrict__ out_f32,
                                                   int N, int last) {
    int wid = (blockIdx.x * blockDim.x + threadIdx.x) >> 6;
    int lane = threadIdx.x & 63;
    if (wid >= N) return;
    int grp = lane >> 3, sub = lane & 7;

    // hoist epilogue operands above the gather loop (latency overlap)
    float isd = is[wid];
    size_t rowo = ((size_t)wid << 6) + (sub << 3);
    uint4 hq = make_uint4(0, 0, 0, 0);
    if (grp == 0) hq = *(const uint4*)(h0h + rowo);

    float acc[8] = {0.f, 0.f, 0.f, 0.f, 0.f, 0.f, 0.f, 0.f};
    for (int qt = 0; qt < NQT; ++qt) {
        int base = rowq[qt * (N + 1) + wid];
        int end = rowq[qt * (N + 1) + wid + 1];
        for (int b = base; b < end; b += 16) {
            int e0 = b + grp;
            int e1 = e0 + 8;
            bool v0 = e0 < end;
            bool v1 = e1 < end;
            uint4 q0, q1;
            int s0, s1;
            if (v0) s0 = csr_src[e0];
            if (v1) s1 = csr_src[e1];
            if (v0) q0 = *(const uint4*)(u_in + ((size_t)s0 << 6) + (sub << 3));
            if (v1) q1 = *(const uint4*)(u_in + ((size_t)s1 << 6) + (sub << 3));
            if (v0) {
                const __half2* hp = (const __half2*)&q0;
#pragma unroll
                for (int k = 0; k < 4; ++k) {
                    float2 f2 = __half22float2(hp[k]);
                    acc[2 * k] += f2.x;
                    acc[2 * k + 1] += f2.y;
                }
            }
            if (v1) {
                const __half2* hp = (const __half2*)&q1;
#pragma unroll
                for (int k = 0; k < 4; ++k) {
                    float2 f2 = __half22float2(hp[k]);
                    acc[2 * k] += f2.x;
                    acc[2 * k + 1] += f2.y;
                }
            }
        }
    }
#pragma unroll
    for (int j = 0; j < 8; ++j) {
        acc[j] += __shfl_xor(acc[j], 8);
        acc[j] += __shfl_xor(acc[j], 16);
        acc[j] += __shfl_xor(acc[j], 32);
    }
    if (grp == 0) {
        const __half2* hp = (const __half2*)&hq;
        float h[8];
#pragma unroll
        for (int k = 0; k < 4; ++k) {
            float2 f2 = __half22float2(hp[k]);
            h[2 * k] = f2.x;
            h[2 * k + 1] = f2.y;
        }
        if (last) {
            float r[8];
#pragma unroll
            for (int j = 0; j < 8; ++j) r[j] = (1.0f - ALPHA) * isd * acc[j] + ALPHA * h[j];
            *(float4*)(out_f32 + rowo) = make_float4(r[0], r[1], r[2], r[3]);
            *(float4*)(out_f32 + rowo + 4) = make_float4(r[4], r[5], r[6], r[7]);
        } else {
            __half2 w[4];
#pragma unroll
            for (int k = 0; k < 4; ++k) {
                float a = ((1.0f - ALPHA) * isd * acc[2 * k] + ALPHA * h[2 * k]) * isd;
                float b = ((1.0f - ALPHA) * isd * acc[2 * k + 1] + ALPHA * h[2 * k + 1]) * isd;
                w[k] = __floats2half2_rn(a, b);
            }
            *(uint4*)(u_out + rowo) = *(uint4*)w;
        }
    }
}

extern "C" void kernel_launch(void* const* d_in, const int* in_sizes, int n_in,
                              void* d_out, int out_size, void* d_ws, size_t ws_size,
                              hipStream_t stream) {
    const float* x = (const float*)d_in[0];
    const int* edges = (const int*)d_in[1];
    const float* W1 = (const float*)d_in[2];
    const float* b1 = (const float*)d_in[3];
    const float* W2 = (const float*)d_in[4];
    const float* b2 = (const float*)d_in[5];
    float* out = (float*)d_out;

    const int N = in_sizes[0] / FEATS;   // 100000
    const int E = in_sizes[1] / 2;       // 1600000
    const int NB = (N + BUCKET - 1) >> BUCKET_BITS;   // 391
    const int NK = NQT * NB;                          // 1564
    const int* src = edges;
    const int* dst = edges + E;

    char* ws = (char*)d_ws;
    size_t off = 0;
    auto alloc = [&](size_t bytes) {
        char* p = ws + off;
        off = (off + bytes + 255) & ~(size_t)255;
        return p;
    };
    int* part = (int*)alloc((size_t)E * 4);
    int* csr_src = (int*)alloc((size_t)E * 4);
    int* bcnt = (int*)alloc((size_t)NK * 4);
    int* bptr = (int*)alloc((size_t)(NK + 1) * 4);
    int* gcur = (int*)alloc((size_t)NK * 4);
    int* rowq = (int*)alloc((size_t)NQT * (N + 1) * 4);
    float* inv_sqrt = (float*)alloc((size_t)N * 4);
    __half* h0h = (__half*)alloc((size_t)N * CLASSES * 2);
    __half* uA = (__half*)alloc((size_t)N * CLASSES * 2);
    __half* uB = (__half*)alloc((size_t)N * CLASSES * 2);
    unsigned short* w1h = (unsigned short*)alloc(4096 * 8 * 2);
    unsigned short* w1l = (unsigned short*)alloc(4096 * 8 * 2);
    unsigned short* w2h = (unsigned short*)alloc(512 * 8 * 2);
    unsigned short* w2l = (unsigned short*)alloc(512 * 8 * 2);
    (void)ws_size;

    // ---- CSR build keyed by (src quartile, dst bucket) ----
    hipMemsetAsync(bcnt, 0, (size_t)NK * 4, stream);
    bucket_hist_kernel<<<128, 256, 0, stream>>>(src, dst, bcnt, NB, NK, E);
    bucket_scan_kernel<<<1, 1024, 0, stream>>>(bcnt, bptr, gcur, rowq, NB, NK, N, E);
    int k3_blocks = (E + K3_CHUNK - 1) / K3_CHUNK;
    bucket_scatter_kernel<<<k3_blocks, K3_THREADS, 0, stream>>>(src, dst, gcur, part, NB, NK, E);
    part_to_csr_kernel<<<NK, 256, 0, stream>>>(bptr, part, rowq, csr_src, NB, N);
    norm_kernel<<<(N + 255) / 256, 256, 0, stream>>>(rowq, inv_sqrt, N);

    // ---- MLP -> h0 (fp16) + u0 = h0*is ----
    pack_w_kernel<<<18, 256, 0, stream>>>(W1, W2, w1h, w1l, w2h, w2l);
    int tiles = (N + 15) / 16;
    mlp_mfma_kernel<<<(tiles + 3) / 4, 256, 0, stream>>>(x, w1h, w1l, b1, w2h, w2l, b2,
                                                         inv_sqrt, h0h, uA, N);

    // ---- 10 propagation rounds ----
    int blocks = (N * 64 + 255) / 256;
    for (int d = 0; d < DEPTH; ++d) {
        const __half* uin = (d & 1) ? uB : uA;
        __half* uout = (d & 1) ? uA : uB;
        int last = (d == DEPTH - 1);
        prop_kernel<<<blocks, 256, 0, stream>>>(rowq, csr_src, inv_sqrt, uin, h0h,
                                                uout, out, N, last);
    }
}

// Round 10
// 549.070 us; speedup vs baseline: 1.4387x; 1.4387x over previous
//
#include <hip/hip_runtime.h>
#include <hip/hip_fp16.h>

#define FEATS 512
#define HIDDEN 64
#define CLASSES 64
#define DEPTH 10
#define ALPHA 0.1f

#define BUCKET_BITS 8
#define BUCKET 256
#define NB_C 391         // ceil(100000 / 256) buckets of 256 nodes
#define K3_CHUNK 8192
#define K3_THREADS 512

typedef __attribute__((ext_vector_type(8))) short short8;
typedef __attribute__((ext_vector_type(4))) float f32x4;

__device__ __forceinline__ unsigned short bf16_hi(float f) {
    unsigned u = __float_as_uint(f);
    unsigned r = u + 0x7FFF + ((u >> 16) & 1);   // RNE
    return (unsigned short)(r >> 16);
}
__device__ __forceinline__ float bf16_tof(unsigned short h) {
    return __uint_as_float(((unsigned)h) << 16);
}

// ---------------- K1: bucket histogram (LDS-aggregated) ----------------
__global__ __launch_bounds__(256) void bucket_hist_kernel(const int* __restrict__ dst,
                                                          int* __restrict__ bcnt,
                                                          int NB, int E) {
    __shared__ int h[NB_C];
    for (int j = threadIdx.x; j < NB; j += 256) h[j] = 0;
    __syncthreads();
    int i = blockIdx.x * 256 + threadIdx.x;
    int stride = gridDim.x * 256;
    for (; i < E; i += stride) atomicAdd(&h[dst[i] >> BUCKET_BITS], 1);
    __syncthreads();
    for (int j = threadIdx.x; j < NB; j += 256) {
        int v = h[j];
        if (v) atomicAdd(&bcnt[j], v);
    }
}

// ---------------- K2: scan bucket counts -> bptr, gcursor ----------------
__global__ __launch_bounds__(1024) void bucket_scan_kernel(const int* __restrict__ bcnt,
                                                           int* __restrict__ bptr,
                                                           int* __restrict__ gcur,
                                                           int* __restrict__ rowptr,
                                                           int NB, int N, int E) {
    __shared__ int sd[1024];
    int t = threadIdx.x;
    int i0 = 2 * t, i1 = 2 * t + 1;
    int a = (i0 < NB) ? bcnt[i0] : 0;
    int b = (i1 < NB) ? bcnt[i1] : 0;
    int s = a + b;
    sd[t] = s;
    __syncthreads();
    for (int off = 1; off < 1024; off <<= 1) {
        int v = (t >= off) ? sd[t - off] : 0;
        __syncthreads();
        sd[t] += v;
        __syncthreads();
    }
    int excl = sd[t] - s;
    if (i0 < NB) { bptr[i0] = excl;     gcur[i0] = excl; }
    if (i1 < NB) { bptr[i1] = excl + a; gcur[i1] = excl + a; }
    if (t == 0) { bptr[NB] = E; rowptr[N] = E; }
}

// ---------------- K3: partition edges into buckets (packed src|ldst) ----------
__global__ __launch_bounds__(K3_THREADS) void bucket_scatter_kernel(const int* __restrict__ src,
                                                                    const int* __restrict__ dst,
                                                                    int* __restrict__ gcur,
                                                                    int* __restrict__ part,
                                                                    int NB, int E) {
    __shared__ int hist[NB_C];
    __shared__ int base[NB_C];
    int cbase = blockIdx.x * K3_CHUNK;
    for (int j = threadIdx.x; j < NB; j += K3_THREADS) hist[j] = 0;
    __syncthreads();
    for (int k = 0; k < K3_CHUNK; k += K3_THREADS) {
        int i = cbase + k + threadIdx.x;
        if (i < E) atomicAdd(&hist[dst[i] >> BUCKET_BITS], 1);
    }
    __syncthreads();
    for (int j = threadIdx.x; j < NB; j += K3_THREADS) {
        int h = hist[j];
        base[j] = (h > 0) ? atomicAdd(&gcur[j], h) : 0;
        hist[j] = 0;   // reuse as local cursor
    }
    __syncthreads();
    for (int k = 0; k < K3_CHUNK; k += K3_THREADS) {
        int i = cbase + k + threadIdx.x;
        if (i < E) {
            int d = dst[i];
            int j = d >> BUCKET_BITS;
            int off = atomicAdd(&hist[j], 1);
            part[(size_t)(base[j] + off)] = (src[i] << BUCKET_BITS) | (d & (BUCKET - 1));
        }
    }
}

// ---------------- K4: per-bucket exact CSR + degrees + inv_sqrt ----------------
__global__ __launch_bounds__(256) void part_to_csr_kernel(const int* __restrict__ bptr,
                                                          const int* __restrict__ part,
                                                          int* __restrict__ rowptr,
                                                          float* __restrict__ inv_sqrt,
                                                          int* __restrict__ csr_src,
                                                          int N) {
    __shared__ int cnt[BUCKET];
    __shared__ int cur[BUCKET];
    __shared__ int wsum[4];
    int b = blockIdx.x;
    int lo = b << BUCKET_BITS;
    int tid = threadIdx.x;
    int p0 = bptr[b], p1 = bptr[b + 1];
    cnt[tid] = 0;
    __syncthreads();
    for (int i = p0 + tid; i < p1; i += 256) {
        atomicAdd(&cnt[part[i] & (BUCKET - 1)], 1);
    }
    __syncthreads();
    {
        int wv = tid >> 6, ln = tid & 63;
        int v = cnt[tid];
        int incl = v;
#pragma unroll
        for (int off = 1; off < 64; off <<= 1) {
            int t = __shfl_up(incl, off);
            if (ln >= off) incl += t;
        }
        if (ln == 63) wsum[wv] = incl;
        __syncthreads();
        int woff = 0;
#pragma unroll
        for (int w = 0; w < 4; ++w)
            if (w < wv) woff += wsum[w];
        int excl = woff + incl - v;
        if (lo + tid < N) {
            rowptr[lo + tid] = p0 + excl;
            inv_sqrt[lo + tid] = rsqrtf((float)(v < 1 ? 1 : v));
        }
        cur[tid] = excl;
    }
    __syncthreads();
    for (int i = p0 + tid; i < p1; i += 256) {
        int pe = part[i];
        int off = atomicAdd(&cur[pe & (BUCKET - 1)], 1);
        csr_src[p0 + off] = ((unsigned)pe) >> BUCKET_BITS;
    }
}

// ---------------- pack W1/W2 into MFMA B-fragment order, split bf16 hi/lo ----
__global__ __launch_bounds__(256) void pack_w_kernel(const float* __restrict__ W1,
                                                     const float* __restrict__ W2,
                                                     unsigned short* __restrict__ w1h,
                                                     unsigned short* __restrict__ w1l,
                                                     unsigned short* __restrict__ w2h,
                                                     unsigned short* __restrict__ w2l) {
    int id = blockIdx.x * blockDim.x + threadIdx.x;
    if (id < 4096) {
        int lane = id & 63, f = (id >> 6) & 3, ks = id >> 8;
        int col = f * 16 + (lane & 15);
        int k0 = ks * 32 + (lane >> 4) * 8;
#pragma unroll
        for (int i = 0; i < 8; ++i) {
            float v = W1[(k0 + i) * HIDDEN + col];
            unsigned short h = bf16_hi(v);
            w1h[id * 8 + i] = h;
            w1l[id * 8 + i] = bf16_hi(v - bf16_tof(h));
        }
    } else if (id < 4096 + 512) {
        int p = id - 4096;
        int lane = p & 63, f = (p >> 6) & 3, ks = p >> 8;
        int col = f * 16 + (lane & 15);
        int k0 = ks * 32 + (lane >> 4) * 8;
#pragma unroll
        for (int i = 0; i < 8; ++i) {
            float v = W2[(k0 + i) * CLASSES + col];
            unsigned short h = bf16_hi(v);
            w2h[p * 8 + i] = h;
            w2l[p * 8 + i] = bf16_hi(v - bf16_tof(h));
        }
    }
}

// ------- MLP via split-bf16 MFMA: h0 = relu(x@W1+b1)@W2+b2; also u0 = h0*is --
__global__ __launch_bounds__(256) void mlp_mfma_kernel(const float* __restrict__ x,
                                                       const unsigned short* __restrict__ w1h,
                                                       const unsigned short* __restrict__ w1l,
                                                       const float* __restrict__ b1,
                                                       const unsigned short* __restrict__ w2h,
                                                       const unsigned short* __restrict__ w2l,
                                                       const float* __restrict__ b2,
                                                       const float* __restrict__ is,
                                                       __half* __restrict__ h0h,
                                                       __half* __restrict__ u0,
                                                       int N) {
    __shared__ float hs[4][16][68];
    int wave = threadIdx.x >> 6;
    int lane = threadIdx.x & 63;
    int tile = blockIdx.x * 4 + wave;
    if (tile * 16 >= N) return;

    int row = lane & 15;
    int koff = (lane >> 4) * 8;
    const short8* w1hv = (const short8*)w1h;
    const short8* w1lv = (const short8*)w1l;
    const short8* w2hv = (const short8*)w2h;
    const short8* w2lv = (const short8*)w2l;

    f32x4 c[4] = {};
    const float* xrow = x + (size_t)(tile * 16 + row) * FEATS + koff;
#pragma unroll 4
    for (int ks = 0; ks < 16; ++ks) {
        float4 a0 = *(const float4*)(xrow + ks * 32);
        float4 a1 = *(const float4*)(xrow + ks * 32 + 4);
        float av[8] = {a0.x, a0.y, a0.z, a0.w, a1.x, a1.y, a1.z, a1.w};
        short8 ah, al;
#pragma unroll
        for (int j = 0; j < 8; ++j) {
            unsigned short h = bf16_hi(av[j]);
            ah[j] = (short)h;
            al[j] = (short)bf16_hi(av[j] - bf16_tof(h));
        }
#pragma unroll
        for (int f = 0; f < 4; ++f) {
            short8 bh = w1hv[(ks * 4 + f) * 64 + lane];
            short8 bl = w1lv[(ks * 4 + f) * 64 + lane];
            c[f] = __builtin_amdgcn_mfma_f32_16x16x32_bf16(ah, bh, c[f], 0, 0, 0);
            c[f] = __builtin_amdgcn_mfma_f32_16x16x32_bf16(ah, bl, c[f], 0, 0, 0);
            c[f] = __builtin_amdgcn_mfma_f32_16x16x32_bf16(al, bh, c[f], 0, 0, 0);
        }
    }
#pragma unroll
    for (int f = 0; f < 4; ++f) {
        float bias = b1[f * 16 + (lane & 15)];
#pragma unroll
        for (int r = 0; r < 4; ++r) {
            hs[wave][(lane >> 4) * 4 + r][f * 16 + (lane & 15)] = fmaxf(c[f][r] + bias, 0.0f);
        }
    }

    f32x4 c2[4] = {};
#pragma unroll
    for (int ks = 0; ks < 2; ++ks) {
        float4 a0 = *(const float4*)&hs[wave][row][ks * 32 + koff];
        float4 a1 = *(const float4*)&hs[wave][row][ks * 32 + koff + 4];
        float av[8] = {a0.x, a0.y, a0.z, a0.w, a1.x, a1.y, a1.z, a1.w};
        short8 ah, al;
#pragma unroll
        for (int j = 0; j < 8; ++j) {
            unsigned short h = bf16_hi(av[j]);
            ah[j] = (short)h;
            al[j] = (short)bf16_hi(av[j] - bf16_tof(h));
        }
#pragma unroll
        for (int f = 0; f < 4; ++f) {
            short8 bh = w2hv[(ks * 4 + f) * 64 + lane];
            short8 bl = w2lv[(ks * 4 + f) * 64 + lane];
            c2[f] = __builtin_amdgcn_mfma_f32_16x16x32_bf16(ah, bh, c2[f], 0, 0, 0);
            c2[f] = __builtin_amdgcn_mfma_f32_16x16x32_bf16(ah, bl, c2[f], 0, 0, 0);
            c2[f] = __builtin_amdgcn_mfma_f32_16x16x32_bf16(al, bh, c2[f], 0, 0, 0);
        }
    }
    float isv[4];
#pragma unroll
    for (int r = 0; r < 4; ++r) {
        int n = tile * 16 + (lane >> 4) * 4 + r;
        isv[r] = is[n];
    }
#pragma unroll
    for (int f = 0; f < 4; ++f) {
        float bias = b2[f * 16 + (lane & 15)];
#pragma unroll
        for (int r = 0; r < 4; ++r) {
            int n = tile * 16 + (lane >> 4) * 4 + r;
            float v = c2[f][r] + bias;
            h0h[(size_t)n * CLASSES + f * 16 + (lane & 15)] = __float2half(v);
            u0[(size_t)n * CLASSES + f * 16 + (lane & 15)] = __float2half(v * isv[r]);
        }
    }
}

// -------- propagation: h = 0.9*is[d]*sum(u[src]) + alpha*h0; u_out = h*is[d] --
// wave per node; grp=lane>>3 selects edge, sub=lane&7 selects 8-feature slice:
// one dwordx4 gathers 8 full rows per wave-instruction. Gathers exec-masked.
__global__ __launch_bounds__(256) void prop_kernel(const int* __restrict__ rowptr,
                                                   const int* __restrict__ csr_src,
                                                   const float* __restrict__ is,
                                                   const __half* __restrict__ u_in,
                                                   const __half* __restrict__ h0h,
                                                   __half* __restrict__ u_out,
                                                   float* __restrict__ out_f32,
                                                   int N, int last) {
    int wid = (blockIdx.x * blockDim.x + threadIdx.x) >> 6;
    int lane = threadIdx.x & 63;
    if (wid >= N) return;
    int base = rowptr[wid];
    int end = rowptr[wid + 1];
    int grp = lane >> 3, sub = lane & 7;

    // hoist epilogue operands above the gather loop (latency overlap)
    float isd = is[wid];
    size_t rowo = ((size_t)wid << 6) + (sub << 3);
    uint4 hq = make_uint4(0, 0, 0, 0);
    if (grp == 0) hq = *(const uint4*)(h0h + rowo);

    float acc[8] = {0.f, 0.f, 0.f, 0.f, 0.f, 0.f, 0.f, 0.f};
    for (int b = base; b < end; b += 16) {
        int e0 = b + grp;
        int e1 = e0 + 8;
        bool v0 = e0 < end;
        bool v1 = e1 < end;
        uint4 q0, q1;
        int s0, s1;
        if (v0) s0 = csr_src[e0];
        if (v1) s1 = csr_src[e1];
        if (v0) q0 = *(const uint4*)(u_in + ((size_t)s0 << 6) + (sub << 3));
        if (v1) q1 = *(const uint4*)(u_in + ((size_t)s1 << 6) + (sub << 3));
        if (v0) {
            const __half2* hp = (const __half2*)&q0;
#pragma unroll
            for (int k = 0; k < 4; ++k) {
                float2 f2 = __half22float2(hp[k]);
                acc[2 * k] += f2.x;
                acc[2 * k + 1] += f2.y;
            }
        }
        if (v1) {
            const __half2* hp = (const __half2*)&q1;
#pragma unroll
            for (int k = 0; k < 4; ++k) {
                float2 f2 = __half22float2(hp[k]);
                acc[2 * k] += f2.x;
                acc[2 * k + 1] += f2.y;
            }
        }
    }
#pragma unroll
    for (int j = 0; j < 8; ++j) {
        acc[j] += __shfl_xor(acc[j], 8);
        acc[j] += __shfl_xor(acc[j], 16);
        acc[j] += __shfl_xor(acc[j], 32);
    }
    if (grp == 0) {
        const __half2* hp = (const __half2*)&hq;
        float h[8];
#pragma unroll
        for (int k = 0; k < 4; ++k) {
            float2 f2 = __half22float2(hp[k]);
            h[2 * k] = f2.x;
            h[2 * k + 1] = f2.y;
        }
        if (last) {
            float r[8];
#pragma unroll
            for (int j = 0; j < 8; ++j) r[j] = (1.0f - ALPHA) * isd * acc[j] + ALPHA * h[j];
            *(float4*)(out_f32 + rowo) = make_float4(r[0], r[1], r[2], r[3]);
            *(float4*)(out_f32 + rowo + 4) = make_float4(r[4], r[5], r[6], r[7]);
        } else {
            __half2 w[4];
#pragma unroll
            for (int k = 0; k < 4; ++k) {
                float a = ((1.0f - ALPHA) * isd * acc[2 * k] + ALPHA * h[2 * k]) * isd;
                float b = ((1.0f - ALPHA) * isd * acc[2 * k + 1] + ALPHA * h[2 * k + 1]) * isd;
                w[k] = __floats2half2_rn(a, b);
            }
            *(uint4*)(u_out + rowo) = *(uint4*)w;
        }
    }
}

extern "C" void kernel_launch(void* const* d_in, const int* in_sizes, int n_in,
                              void* d_out, int out_size, void* d_ws, size_t ws_size,
                              hipStream_t stream) {
    const float* x = (const float*)d_in[0];
    const int* edges = (const int*)d_in[1];
    const float* W1 = (const float*)d_in[2];
    const float* b1 = (const float*)d_in[3];
    const float* W2 = (const float*)d_in[4];
    const float* b2 = (const float*)d_in[5];
    float* out = (float*)d_out;

    const int N = in_sizes[0] / FEATS;   // 100000
    const int E = in_sizes[1] / 2;       // 1600000
    const int NB = (N + BUCKET - 1) >> BUCKET_BITS;   // 391
    const int* src = edges;
    const int* dst = edges + E;

    char* ws = (char*)d_ws;
    size_t off = 0;
    auto alloc = [&](size_t bytes) {
        char* p = ws + off;
        off = (off + bytes + 255) & ~(size_t)255;
        return p;
    };
    int* part = (int*)alloc((size_t)E * 4);
    int* csr_src = (int*)alloc((size_t)E * 4);
    int* bcnt = (int*)alloc((size_t)NB * 4);
    int* bptr = (int*)alloc((size_t)(NB + 1) * 4);
    int* gcur = (int*)alloc((size_t)NB * 4);
    int* rowptr = (int*)alloc((size_t)(N + 1) * 4);
    float* inv_sqrt = (float*)alloc((size_t)N * 4);
    __half* h0h = (__half*)alloc((size_t)N * CLASSES * 2);
    __half* uA = (__half*)alloc((size_t)N * CLASSES * 2);
    __half* uB = (__half*)alloc((size_t)N * CLASSES * 2);
    unsigned short* w1h = (unsigned short*)alloc(4096 * 8 * 2);
    unsigned short* w1l = (unsigned short*)alloc(4096 * 8 * 2);
    unsigned short* w2h = (unsigned short*)alloc(512 * 8 * 2);
    unsigned short* w2l = (unsigned short*)alloc(512 * 8 * 2);
    (void)ws_size;

    // ---- CSR build (two-level bucket sort, 256-node buckets) ----
    hipMemsetAsync(bcnt, 0, (size_t)NB * 4, stream);
    bucket_hist_kernel<<<128, 256, 0, stream>>>(dst, bcnt, NB, E);
    bucket_scan_kernel<<<1, 1024, 0, stream>>>(bcnt, bptr, gcur, rowptr, NB, N, E);
    int k3_blocks = (E + K3_CHUNK - 1) / K3_CHUNK;
    bucket_scatter_kernel<<<k3_blocks, K3_THREADS, 0, stream>>>(src, dst, gcur, part, NB, E);
    part_to_csr_kernel<<<NB, 256, 0, stream>>>(bptr, part, rowptr, inv_sqrt, csr_src, N);

    // ---- MLP -> h0 (fp16) + u0 = h0*is ----
    pack_w_kernel<<<18, 256, 0, stream>>>(W1, W2, w1h, w1l, w2h, w2l);
    int tiles = (N + 15) / 16;
    mlp_mfma_kernel<<<(tiles + 3) / 4, 256, 0, stream>>>(x, w1h, w1l, b1, w2h, w2l, b2,
                                                         inv_sqrt, h0h, uA, N);

    // ---- 10 propagation rounds ----
    int blocks = (N * 64 + 255) / 256;
    for (int d = 0; d < DEPTH; ++d) {
        const __half* uin = (d & 1) ? uB : uA;
        __half* uout = (d & 1) ? uA : uB;
        int last = (d == DEPTH - 1);
        prop_kernel<<<blocks, 256, 0, stream>>>(rowptr, csr_src, inv_sqrt, uin, h0h,
                                                uout, out, N, last);
    }
}